// Round 1
// baseline (50.362 us; speedup 1.0000x reference)
//
#include <hip/hip_runtime.h>
#include <math.h>

// Problem constants (from reference):
constexpr int Bn = 1024;
constexpr int S  = 512;
constexpr int H  = 768;
constexpr int D1 = 128;
constexpr int HV = H / 4;     // 192 float4 per feature row
constexpr int POOL_T = HV;    // 192 threads = 3 waves, one float4 column each

// Kernel 1: per-example CLS extract + ragged span mean-pool.
// G[b][0:768] = features[b,0,:], G[b][768:1536] = mean(features[b,start:end,:])
__global__ __launch_bounds__(POOL_T) void pool_kernel(
    const float* __restrict__ feat, const int* __restrict__ start,
    const int* __restrict__ endp, float* __restrict__ G) {
  const int b = blockIdx.x;
  const int t = threadIdx.x;  // 0..191, one float4 column
  const float4* base = reinterpret_cast<const float4*>(feat) + (size_t)b * (S * HV);

  float4 cls = base[t];  // row 0

  const int s0 = start[b];
  const int s1 = endp[b];
  float4 acc = make_float4(0.f, 0.f, 0.f, 0.f);
  for (int s = s0; s < s1; ++s) {
    float4 v = base[(size_t)s * HV + t];
    acc.x += v.x; acc.y += v.y; acc.z += v.z; acc.w += v.w;
  }
  const float inv = 1.0f / (float)(s1 - s0);
  acc.x *= inv; acc.y *= inv; acc.z *= inv; acc.w *= inv;

  float4* Gv = reinterpret_cast<float4*>(G) + (size_t)b * (2 * HV);
  Gv[t] = cls;        // cls half
  Gv[HV + t] = acc;   // crc half
}

// Kernel 2: MLP head. 4 examples per block, 256 threads.
// h[e][k] = relu(b1[k] + sum_d g[e][d] * W1[d][k]); out[e] = sigmoid(b2 + sum_k h*W2[k])
__global__ __launch_bounds__(256) void head_kernel(
    const float* __restrict__ G, const float* __restrict__ W1,
    const float* __restrict__ b1, const float* __restrict__ W2,
    const float* __restrict__ b2, float* __restrict__ out) {
  __shared__ float g[4][2 * H];      // 24 KB: 4 examples' concat features
  __shared__ float part[2][4][D1];   // 4 KB: per-half partial dots
  __shared__ float wsum[2][4];       // cross-wave reduce scratch

  const int t = threadIdx.x;
  const int e0 = blockIdx.x * 4;

  // Stage G for 4 examples (coalesced float4)
  const float4* Gv = reinterpret_cast<const float4*>(G + (size_t)e0 * 2 * H);
  float4* gv = reinterpret_cast<float4*>(&g[0][0]);
  for (int i = t; i < 4 * 2 * H / 4; i += 256) gv[i] = Gv[i];
  __syncthreads();

  const int k = t & (D1 - 1);   // output unit 0..127
  const int half = t >> 7;      // d-range half: 0 -> [0,768), 1 -> [768,1536)
  const int dbase = half * H;
  const float* Wcol = W1 + (size_t)dbase * D1 + k;

  float a0 = 0.f, a1 = 0.f, a2 = 0.f, a3 = 0.f;
  #pragma unroll 4
  for (int d = 0; d < H; d += 4) {
    // W1 reads: wave reads 64 consecutive floats per d -> coalesced, L2-resident
    float w0 = Wcol[(size_t)(d + 0) * D1];
    float w1v = Wcol[(size_t)(d + 1) * D1];
    float w2v = Wcol[(size_t)(d + 2) * D1];
    float w3v = Wcol[(size_t)(d + 3) * D1];
    // g reads: same address across lanes of a half -> LDS broadcast (free)
    float4 g0 = *reinterpret_cast<const float4*>(&g[0][dbase + d]);
    float4 g1 = *reinterpret_cast<const float4*>(&g[1][dbase + d]);
    float4 g2 = *reinterpret_cast<const float4*>(&g[2][dbase + d]);
    float4 g3 = *reinterpret_cast<const float4*>(&g[3][dbase + d]);
    a0 += g0.x * w0 + g0.y * w1v + g0.z * w2v + g0.w * w3v;
    a1 += g1.x * w0 + g1.y * w1v + g1.z * w2v + g1.w * w3v;
    a2 += g2.x * w0 + g2.y * w1v + g2.z * w2v + g2.w * w3v;
    a3 += g3.x * w0 + g3.y * w1v + g3.z * w2v + g3.w * w3v;
  }
  part[half][0][k] = a0;
  part[half][1][k] = a1;
  part[half][2][k] = a2;
  part[half][3][k] = a3;
  __syncthreads();

  if (t < D1) {
    const float bb = b1[t];
    const float w2k = W2[t];
    float v[4];
    #pragma unroll
    for (int e = 0; e < 4; ++e) {
      float h = bb + part[0][e][t] + part[1][e][t];
      h = h > 0.f ? h : 0.f;
      v[e] = h * w2k;
    }
    // reduce over the 128 k-threads: butterfly within each wave64, then LDS
    #pragma unroll
    for (int off = 32; off > 0; off >>= 1) {
      #pragma unroll
      for (int e = 0; e < 4; ++e) v[e] += __shfl_down(v[e], off);
    }
    if ((t & 63) == 0) {
      const int w = t >> 6;
      #pragma unroll
      for (int e = 0; e < 4; ++e) wsum[w][e] = v[e];
    }
  }
  __syncthreads();

  if (t < 4) {
    float s = wsum[0][t] + wsum[1][t] + b2[0];
    out[e0 + t] = 1.0f / (1.0f + expf(-s));
  }
}

extern "C" void kernel_launch(void* const* d_in, const int* in_sizes, int n_in,
                              void* d_out, int out_size, void* d_ws, size_t ws_size,
                              hipStream_t stream) {
  const float* feat = (const float*)d_in[0];   // [B,S,H] fp32
  const int* start  = (const int*)d_in[1];     // [B] int
  const int* endp   = (const int*)d_in[2];     // [B] int
  const float* W1   = (const float*)d_in[3];   // [2H,D1]
  const float* b1   = (const float*)d_in[4];   // [D1]
  const float* W2   = (const float*)d_in[5];   // [D1,1]
  const float* b2   = (const float*)d_in[6];   // [1]
  float* out = (float*)d_out;                  // [B] (B,1,1 flattened)
  float* G = (float*)d_ws;                     // [B][1536] scratch, 6 MB

  hipLaunchKernelGGL(pool_kernel, dim3(Bn), dim3(POOL_T), 0, stream,
                     feat, start, endp, G);
  hipLaunchKernelGGL(head_kernel, dim3(Bn / 4), dim3(256), 0, stream,
                     G, W1, b1, W2, b2, out);
}

// Round 2
// 39.569 us; speedup vs baseline: 1.2728x; 1.2728x over previous
//
#include <hip/hip_runtime.h>
#include <math.h>

// Problem constants (from reference):
constexpr int Bn = 1024;
constexpr int S  = 512;
constexpr int H  = 768;
constexpr int D1 = 128;
constexpr int HV = H / 4;     // 192 float4 per feature row

// ws layout (floats):
//   cls [Bn][H]        — CLS features
//   gp  [2][Bn][H]     — span-mean partial sums (even/odd rows), pre-scaled by 1/len
//   P   [4][Bn][D1]    — per-d-chunk partial h dots

// Kernel 1: ragged span mean-pool, 2 blocks per example (even/odd rows) for
// occupancy + load balance; 4-way unrolled accumulators for memory ILP.
__global__ __launch_bounds__(192) void pool_partial(
    const float* __restrict__ feat, const int* __restrict__ start,
    const int* __restrict__ endp, float* __restrict__ cls,
    float* __restrict__ gp) {
  const int b = blockIdx.x >> 1;
  const int p = blockIdx.x & 1;
  const int t = threadIdx.x;  // 0..191, one float4 column
  const float4* base = reinterpret_cast<const float4*>(feat) + (size_t)b * (S * HV);

  if (p == 0) {
    reinterpret_cast<float4*>(cls)[(size_t)b * HV + t] = base[t];  // CLS row
  }

  const int s0 = start[b];
  const int s1 = endp[b];
  float4 a0 = {0.f,0.f,0.f,0.f}, a1 = {0.f,0.f,0.f,0.f};
  float4 a2 = {0.f,0.f,0.f,0.f}, a3 = {0.f,0.f,0.f,0.f};
  int s = s0 + p;
  // 4 rows (stride 2) in flight per iteration -> 4 independent loads/wave
  for (; s + 6 < s1; s += 8) {
    float4 v0 = base[(size_t)(s    ) * HV + t];
    float4 v1 = base[(size_t)(s + 2) * HV + t];
    float4 v2 = base[(size_t)(s + 4) * HV + t];
    float4 v3 = base[(size_t)(s + 6) * HV + t];
    a0.x += v0.x; a0.y += v0.y; a0.z += v0.z; a0.w += v0.w;
    a1.x += v1.x; a1.y += v1.y; a1.z += v1.z; a1.w += v1.w;
    a2.x += v2.x; a2.y += v2.y; a2.z += v2.z; a2.w += v2.w;
    a3.x += v3.x; a3.y += v3.y; a3.z += v3.z; a3.w += v3.w;
  }
  for (; s < s1; s += 2) {
    float4 v = base[(size_t)s * HV + t];
    a0.x += v.x; a0.y += v.y; a0.z += v.z; a0.w += v.w;
  }
  const float inv = 1.0f / (float)(s1 - s0);
  float4 r;
  r.x = (a0.x + a1.x + a2.x + a3.x) * inv;
  r.y = (a0.y + a1.y + a2.y + a3.y) * inv;
  r.z = (a0.z + a1.z + a2.z + a3.z) * inv;
  r.w = (a0.w + a1.w + a2.w + a3.w) * inv;
  reinterpret_cast<float4*>(gp)[((size_t)p * Bn + b) * HV + t] = r;
}

// Kernel 2: partial W1 dots. Block = (example-group of 4) x (d-chunk of 384).
// Grid 1024 -> 4 blocks/CU = 16 waves/CU for L2-latency hiding.
__global__ __launch_bounds__(256) void head_partial(
    const float* __restrict__ cls, const float* __restrict__ gp,
    const float* __restrict__ W1, float* __restrict__ P) {
  __shared__ float g[4][384];        // 6 KB: 4 examples' d-chunk of features
  __shared__ float part[2][4][D1];   // 4 KB

  const int t  = threadIdx.x;
  const int c  = blockIdx.x & 3;     // d-chunk 0..3
  const int eg = blockIdx.x >> 2;
  const int e0 = eg * 4;
  const int dglob0 = c * 384;

  // Stage g: d in [c*384, c*384+384); d<H -> cls, else crc = gp0+gp1
  for (int i = t; i < 4 * 384 / 4; i += 256) {
    const int e = i / 96;   // 96 float4 per example-chunk
    const int j = i % 96;
    const int d = dglob0 + j * 4;
    float4 v;
    if (d < H) {
      v = reinterpret_cast<const float4*>(cls)[((size_t)(e0 + e) * H + d) >> 2];
    } else {
      const int dd = d - H;
      const float4* gv = reinterpret_cast<const float4*>(gp);
      float4 u0 = gv[((size_t)(e0 + e) * H + dd) >> 2];
      float4 u1 = gv[((size_t)Bn * H + (size_t)(e0 + e) * H + dd) >> 2];
      v.x = u0.x + u1.x; v.y = u0.y + u1.y;
      v.z = u0.z + u1.z; v.w = u0.w + u1.w;
    }
    reinterpret_cast<float4*>(&g[e][0])[j] = v;
  }
  __syncthreads();

  const int k   = t & (D1 - 1);
  const int sub = t >> 7;                 // which 192-row half of the chunk
  const int gofs = sub * 192;
  const float* Wc = W1 + (size_t)(dglob0 + gofs) * D1 + k;

  float a0 = 0.f, a1 = 0.f, a2 = 0.f, a3 = 0.f;
  #pragma unroll 4
  for (int d = 0; d < 192; d += 4) {
    float w0 = Wc[(size_t)(d + 0) * D1];
    float w1 = Wc[(size_t)(d + 1) * D1];
    float w2 = Wc[(size_t)(d + 2) * D1];
    float w3 = Wc[(size_t)(d + 3) * D1];
    float4 g0 = *reinterpret_cast<const float4*>(&g[0][gofs + d]);
    float4 g1 = *reinterpret_cast<const float4*>(&g[1][gofs + d]);
    float4 g2 = *reinterpret_cast<const float4*>(&g[2][gofs + d]);
    float4 g3 = *reinterpret_cast<const float4*>(&g[3][gofs + d]);
    a0 += g0.x * w0 + g0.y * w1 + g0.z * w2 + g0.w * w3;
    a1 += g1.x * w0 + g1.y * w1 + g1.z * w2 + g1.w * w3;
    a2 += g2.x * w0 + g2.y * w1 + g2.z * w2 + g2.w * w3;
    a3 += g3.x * w0 + g3.y * w1 + g3.z * w2 + g3.w * w3;
  }
  part[sub][0][k] = a0;
  part[sub][1][k] = a1;
  part[sub][2][k] = a2;
  part[sub][3][k] = a3;
  __syncthreads();

  if (t < D1) {
    #pragma unroll
    for (int e = 0; e < 4; ++e) {
      P[((size_t)c * Bn + (e0 + e)) * D1 + t] = part[0][e][t] + part[1][e][t];
    }
  }
}

// Kernel 3: combine chunks, relu, dot W2, sigmoid. One wave per example.
__global__ __launch_bounds__(256) void finalize(
    const float* __restrict__ P, const float* __restrict__ b1,
    const float* __restrict__ W2, const float* __restrict__ b2,
    float* __restrict__ out) {
  const int t = threadIdx.x;
  const int w = t >> 6, l = t & 63;
  const int e = blockIdx.x * 4 + w;
  const int k0 = l, k1 = l + 64;
  float h0 = b1[k0], h1 = b1[k1];
  #pragma unroll
  for (int c = 0; c < 4; ++c) {
    h0 += P[((size_t)c * Bn + e) * D1 + k0];
    h1 += P[((size_t)c * Bn + e) * D1 + k1];
  }
  h0 = fmaxf(h0, 0.f); h1 = fmaxf(h1, 0.f);
  float v = h0 * W2[k0] + h1 * W2[k1];
  #pragma unroll
  for (int off = 32; off > 0; off >>= 1) v += __shfl_down(v, off);
  if (l == 0) out[e] = 1.0f / (1.0f + expf(-(v + b2[0])));
}

extern "C" void kernel_launch(void* const* d_in, const int* in_sizes, int n_in,
                              void* d_out, int out_size, void* d_ws, size_t ws_size,
                              hipStream_t stream) {
  const float* feat = (const float*)d_in[0];   // [B,S,H] fp32
  const int* start  = (const int*)d_in[1];     // [B]
  const int* endp   = (const int*)d_in[2];     // [B]
  const float* W1   = (const float*)d_in[3];   // [2H,D1]
  const float* b1   = (const float*)d_in[4];   // [D1]
  const float* W2   = (const float*)d_in[5];   // [D1,1]
  const float* b2   = (const float*)d_in[6];   // [1]
  float* out = (float*)d_out;                  // [B]

  float* wsf = (float*)d_ws;
  float* cls = wsf;                            // [Bn][H]
  float* gp  = cls + (size_t)Bn * H;           // [2][Bn][H]
  float* P   = gp + (size_t)2 * Bn * H;        // [4][Bn][D1]

  hipLaunchKernelGGL(pool_partial, dim3(Bn * 2), dim3(192), 0, stream,
                     feat, start, endp, cls, gp);
  hipLaunchKernelGGL(head_partial, dim3(Bn), dim3(256), 0, stream,
                     cls, gp, W1, P);
  hipLaunchKernelGGL(finalize, dim3(Bn / 4), dim3(256), 0, stream,
                     P, b1, W2, b2, out);
}